// Round 1
// baseline (411.063 us; speedup 1.0000x reference)
//
#include <hip/hip_runtime.h>

// MIRT pairwise BCE loss.
// Inputs (setup_inputs order): u[B] i32, i[B] i32, s[B] i32,
//   diff[ITEM,1] f32, disc[ITEM,64] f32, theta[USER,64] f32.
// Output: scalar f32 loss.
//
// Layout: 16 lanes cooperate per pair; each lane loads one float4 of the
// 64-float (256 B) theta/disc rows -> one fully-coalesced 256 B segment per
// gather. Butterfly shuffle reduce within the 16-lane group, then block
// reduce + one atomicAdd per block.

__global__ void zero_out_kernel(float* out) { out[0] = 0.0f; }

__global__ __launch_bounds__(256) void mirt_loss_kernel(
    const int* __restrict__ u,
    const int* __restrict__ iidx,
    const int* __restrict__ s,
    const float* __restrict__ diff,
    const float* __restrict__ disc,
    const float* __restrict__ theta,
    float* __restrict__ out,
    int B, float inv_b)
{
    const int lane16 = threadIdx.x & 15;
    const int groupInBlock = threadIdx.x >> 4;
    const int groupsPerBlock = blockDim.x >> 4;   // 16
    const int stride = gridDim.x * groupsPerBlock;
    int pair = blockIdx.x * groupsPerBlock + groupInBlock;

    float acc = 0.0f;
    for (; pair < B; pair += stride) {
        const int uu = u[pair];       // broadcast within the 16-lane group
        const int ii = iidx[pair];
        const float4 t4 = ((const float4*)(theta + (size_t)uu * 64))[lane16];
        const float4 d4 = ((const float4*)(disc  + (size_t)ii * 64))[lane16];
        float p = t4.x * d4.x + t4.y * d4.y + t4.z * d4.z + t4.w * d4.w;
        // reduce partial dot across the 16-lane group (xor butterfly stays
        // within a 16-lane partition)
        p += __shfl_xor(p, 1);
        p += __shfl_xor(p, 2);
        p += __shfl_xor(p, 4);
        p += __shfl_xor(p, 8);
        if (lane16 == 0) {
            const float x = p + diff[ii];
            // BCE(sigmoid(x), s) = softplus((1-2s)*x), stable form
            const float z = (s[pair] != 0) ? -x : x;
            acc += fmaxf(z, 0.0f) + log1pf(__expf(-fabsf(z)));
        }
    }

    // wave (64-lane) butterfly reduce; non-lane16==0 lanes hold 0
    acc += __shfl_xor(acc, 32);
    acc += __shfl_xor(acc, 16);
    acc += __shfl_xor(acc, 8);
    acc += __shfl_xor(acc, 4);
    acc += __shfl_xor(acc, 2);
    acc += __shfl_xor(acc, 1);

    __shared__ float wave_sums[4];
    const int wave = threadIdx.x >> 6;
    const int lane = threadIdx.x & 63;
    if (lane == 0) wave_sums[wave] = acc;
    __syncthreads();
    if (threadIdx.x == 0) {
        const float bs = wave_sums[0] + wave_sums[1] + wave_sums[2] + wave_sums[3];
        atomicAdd(out, bs * inv_b);   // device-scope by default on CDNA
    }
}

extern "C" void kernel_launch(void* const* d_in, const int* in_sizes, int n_in,
                              void* d_out, int out_size, void* d_ws, size_t ws_size,
                              hipStream_t stream) {
    const int*   u     = (const int*)d_in[0];
    const int*   iidx  = (const int*)d_in[1];
    const int*   s     = (const int*)d_in[2];
    const float* diff  = (const float*)d_in[3];
    const float* disc  = (const float*)d_in[4];
    const float* theta = (const float*)d_in[5];
    float* out = (float*)d_out;

    const int B = in_sizes[0];

    zero_out_kernel<<<1, 1, 0, stream>>>(out);

    const int block = 256;
    const int grid = 4096;   // 16 pairs/block/iter -> 16 grid-stride iters at B=1M
    mirt_loss_kernel<<<grid, block, 0, stream>>>(
        u, iidx, s, diff, disc, theta, out, B, 1.0f / (float)B);
}

// Round 2
// 392.035 us; speedup vs baseline: 1.0485x; 1.0485x over previous
//
#include <hip/hip_runtime.h>

// MIRT pairwise BCE loss — two-stage reduction (no same-address atomics).
// Inputs (setup_inputs order): u[B] i32, i[B] i32, s[B] i32,
//   diff[ITEM,1] f32, disc[ITEM,64] f32, theta[USER,64] f32.
// Output: scalar f32 loss.
//
// Stage 1: 16 lanes cooperate per pair; each lane loads one float4 of the
// 64-float (256 B) theta/disc rows -> one fully-coalesced 256 B segment per
// gather. Index loads are software-pipelined one grid-stride iteration ahead.
// Block partial sums land in d_ws[blockIdx.x].
// Stage 2: one block reduces the GRID partials and writes the scaled scalar.

#define GRID_BLOCKS 4096

__global__ __launch_bounds__(256) void mirt_partial_kernel(
    const int* __restrict__ u,
    const int* __restrict__ iidx,
    const int* __restrict__ s,
    const float* __restrict__ diff,
    const float* __restrict__ disc,
    const float* __restrict__ theta,
    float* __restrict__ partials,
    int B)
{
    const int lane16 = threadIdx.x & 15;
    const int groupInBlock = threadIdx.x >> 4;
    const int groupsPerBlock = blockDim.x >> 4;   // 16
    const int stride = gridDim.x * groupsPerBlock;
    int pair = blockIdx.x * groupsPerBlock + groupInBlock;

    // prefetch first iteration's indices
    int uu = 0, ii = 0, ss = 0;
    if (pair < B) { uu = u[pair]; ii = iidx[pair]; ss = s[pair]; }

    float acc = 0.0f;
    for (; pair < B; ) {
        const int npair = pair + stride;
        int nuu = 0, nii = 0, nss = 0;
        if (npair < B) {            // prefetch next iteration's indices NOW,
            nuu = u[npair];         // overlapping with this iteration's gathers
            nii = iidx[npair];
            nss = s[npair];
        }
        const float4 t4 = ((const float4*)(theta + (size_t)uu * 64))[lane16];
        const float4 d4 = ((const float4*)(disc  + (size_t)ii * 64))[lane16];
        const float df  = diff[ii];
        float p = t4.x * d4.x + t4.y * d4.y + t4.z * d4.z + t4.w * d4.w;
        // reduce partial dot across the 16-lane group (xor butterfly stays
        // within a 16-lane partition)
        p += __shfl_xor(p, 1);
        p += __shfl_xor(p, 2);
        p += __shfl_xor(p, 4);
        p += __shfl_xor(p, 8);
        if (lane16 == 0) {
            const float x = p + df;
            // BCE(sigmoid(x), s) = softplus((1-2s)*x), stable form
            const float z = (ss != 0) ? -x : x;
            acc += fmaxf(z, 0.0f) + log1pf(__expf(-fabsf(z)));
        }
        pair = npair; uu = nuu; ii = nii; ss = nss;
    }

    // wave (64-lane) butterfly reduce; lanes with lane16!=0 hold 0
    acc += __shfl_xor(acc, 32);
    acc += __shfl_xor(acc, 16);
    acc += __shfl_xor(acc, 8);
    acc += __shfl_xor(acc, 4);
    acc += __shfl_xor(acc, 2);
    acc += __shfl_xor(acc, 1);

    __shared__ float wave_sums[4];
    const int wave = threadIdx.x >> 6;
    const int lane = threadIdx.x & 63;
    if (lane == 0) wave_sums[wave] = acc;
    __syncthreads();
    if (threadIdx.x == 0) {
        partials[blockIdx.x] =
            wave_sums[0] + wave_sums[1] + wave_sums[2] + wave_sums[3];
    }
}

__global__ __launch_bounds__(256) void mirt_final_kernel(
    const float* __restrict__ partials, float* __restrict__ out,
    int n, float inv_b)
{
    float acc = 0.0f;
    for (int j = threadIdx.x; j < n; j += 256) acc += partials[j];

    acc += __shfl_xor(acc, 32);
    acc += __shfl_xor(acc, 16);
    acc += __shfl_xor(acc, 8);
    acc += __shfl_xor(acc, 4);
    acc += __shfl_xor(acc, 2);
    acc += __shfl_xor(acc, 1);

    __shared__ float wave_sums[4];
    const int wave = threadIdx.x >> 6;
    const int lane = threadIdx.x & 63;
    if (lane == 0) wave_sums[wave] = acc;
    __syncthreads();
    if (threadIdx.x == 0) {
        out[0] = (wave_sums[0] + wave_sums[1] + wave_sums[2] + wave_sums[3])
                 * inv_b;
    }
}

extern "C" void kernel_launch(void* const* d_in, const int* in_sizes, int n_in,
                              void* d_out, int out_size, void* d_ws, size_t ws_size,
                              hipStream_t stream) {
    const int*   u     = (const int*)d_in[0];
    const int*   iidx  = (const int*)d_in[1];
    const int*   s     = (const int*)d_in[2];
    const float* diff  = (const float*)d_in[3];
    const float* disc  = (const float*)d_in[4];
    const float* theta = (const float*)d_in[5];
    float* out      = (float*)d_out;
    float* partials = (float*)d_ws;   // GRID_BLOCKS floats, fully overwritten

    const int B = in_sizes[0];

    mirt_partial_kernel<<<GRID_BLOCKS, 256, 0, stream>>>(
        u, iidx, s, diff, disc, theta, partials, B);
    mirt_final_kernel<<<1, 256, 0, stream>>>(
        partials, out, GRID_BLOCKS, 1.0f / (float)B);
}